// Round 1
// baseline (645.030 us; speedup 1.0000x reference)
//
#include <hip/hip_runtime.h>
#include <stdint.h>

#define BB 2
#define SS 2048
#define HH 1024
#define NHEAD 16
#define HDIM 64

constexpr int   BSROWS = BB * SS;   // 4096
constexpr float SCALE  = 0.125f;    // 1/sqrt(64)
constexpr float LOG2E  = 1.4426950408889634f;

typedef __bf16 bf16;
typedef __attribute__((ext_vector_type(8))) __bf16 bf16x8;
typedef __attribute__((ext_vector_type(4))) __bf16 bf16x4;
typedef __attribute__((ext_vector_type(4))) float  f32x4;

#define MFMA16(a, b, c) __builtin_amdgcn_mfma_f32_16x16x32_bf16((a), (b), (c), 0, 0, 0)

__device__ __forceinline__ void gload_lds16(const void* g, void* l) {
  __builtin_amdgcn_global_load_lds((const __attribute__((address_space(1))) void*)g,
                                   (__attribute__((address_space(3))) void*)l, 16, 0, 0);
}

// ---------------------------------------------------------------- convert inputs
__global__ __launch_bounds__(256) void cvt_in(const float* __restrict__ q, const float* __restrict__ k,
                                              const float* __restrict__ v, const int* __restrict__ mask,
                                              bf16* __restrict__ xq, bf16* __restrict__ xk,
                                              bf16* __restrict__ xv, float* __restrict__ bias) {
  int i = blockIdx.x * 256 + threadIdx.x;
  int e = i * 4;
  f32x4 a = *(const f32x4*)(q + e);
  f32x4 b = *(const f32x4*)(k + e);
  f32x4 c = *(const f32x4*)(v + e);
  *(bf16x4*)(xq + e) = __builtin_convertvector(a, bf16x4);
  *(bf16x4*)(xk + e) = __builtin_convertvector(b, bf16x4);
  *(bf16x4*)(xv + e) = __builtin_convertvector(c, bf16x4);
  if (i < BB * SS) bias[i] = mask[i] ? 0.0f : -1e9f;
}

// ---------------------------------------------------------------- transpose + cast weights: Wt[n][k] = W[k][n]
__global__ __launch_bounds__(256) void cvt_wt(const float* __restrict__ Wq, const float* __restrict__ Wk,
                                              const float* __restrict__ Wv, const float* __restrict__ Wo,
                                              bf16* __restrict__ Wt) {
  __shared__ float tile[32][33];
  int z = blockIdx.z;
  const float* W = (z == 0) ? Wq : (z == 1) ? Wk : (z == 2) ? Wv : Wo;
  bf16* out = Wt + (size_t)z * HH * HH;
  int bx = blockIdx.x * 32, by = blockIdx.y * 32;
  int tx = threadIdx.x, ty = threadIdx.y;
#pragma unroll
  for (int j = 0; j < 32; j += 8)
    tile[ty + j][tx] = W[(size_t)(by + ty + j) * HH + bx + tx];
  __syncthreads();
#pragma unroll
  for (int j = 0; j < 32; j += 8)
    out[(size_t)(bx + ty + j) * HH + by + tx] = (bf16)tile[tx][ty + j];
}

// ---------------------------------------------------------------- 128x128 bf16 GEMM (m97 structure)
// mode <0: blockIdx.z selects projection (0:Q, 1:K, 2:V-transposed); mode==3: f32 row-major out.
__global__ __launch_bounds__(256) void gemm128(const bf16* __restrict__ Abase, const bf16* __restrict__ Btbase,
                                               bf16* __restrict__ Qo, bf16* __restrict__ Ko,
                                               bf16* __restrict__ Vto, float* __restrict__ outF, int mode) {
  int zmode = (mode < 0) ? (int)blockIdx.z : mode;
  const bf16* A  = Abase  + (mode < 0 ? (size_t)blockIdx.z * BSROWS * HH : 0);
  const bf16* Bt = Btbase + (mode < 0 ? (size_t)blockIdx.z * HH * HH : 0);

  __shared__ __align__(16) bf16 lA[128 * 32];
  __shared__ __align__(16) bf16 lB[128 * 32];

  int t = threadIdx.x;
  int w = t >> 6, l = t & 63, lg = l >> 4, lr = l & 15;
  int m0 = blockIdx.y * 128, n0 = blockIdx.x * 128;
  int wr = (w >> 1) * 64, wc = (w & 1) * 64;

  f32x4 zero4 = {0.f, 0.f, 0.f, 0.f};
  f32x4 acc[4][4];
#pragma unroll
  for (int i = 0; i < 4; i++)
#pragma unroll
    for (int j = 0; j < 4; j++) acc[i][j] = zero4;

  for (int k0 = 0; k0 < HH; k0 += 32) {
#pragma unroll
    for (int i = 0; i < 2; i++) {
      int idx = i * 256 + t;
      gload_lds16(A  + (size_t)(m0 + (idx >> 2)) * HH + k0 + (idx & 3) * 8, &lA[(i * 256 + w * 64) * 8]);
      gload_lds16(Bt + (size_t)(n0 + (idx >> 2)) * HH + k0 + (idx & 3) * 8, &lB[(i * 256 + w * 64) * 8]);
    }
    __syncthreads();
    bf16x8 af[4], bq[4];
#pragma unroll
    for (int mi = 0; mi < 4; mi++) af[mi] = *(const bf16x8*)&lA[(wr + mi * 16 + lr) * 32 + lg * 8];
#pragma unroll
    for (int ni = 0; ni < 4; ni++) bq[ni] = *(const bf16x8*)&lB[(wc + ni * 16 + lr) * 32 + lg * 8];
#pragma unroll
    for (int mi = 0; mi < 4; mi++)
#pragma unroll
      for (int ni = 0; ni < 4; ni++)
        acc[mi][ni] = MFMA16(af[mi], bq[ni], acc[mi][ni]);
    __syncthreads();
  }

#pragma unroll
  for (int mi = 0; mi < 4; mi++) {
    int row0 = m0 + wr + mi * 16 + lg * 4;
#pragma unroll
    for (int ni = 0; ni < 4; ni++) {
      int col = n0 + wc + ni * 16 + lr;
      if (zmode == 3) {
#pragma unroll
        for (int r = 0; r < 4; r++) outF[(size_t)(row0 + r) * HH + col] = acc[mi][ni][r];
      } else if (zmode == 2) {
        int b = row0 >> 11, s0 = row0 & (SS - 1);
        int h = col >> 6, d = col & 63;
        bf16x4 pk;
#pragma unroll
        for (int r = 0; r < 4; r++) pk[r] = (bf16)acc[mi][ni][r];
        *(bf16x4*)&Vto[((size_t)(b * NHEAD + h) * HDIM + d) * SS + s0] = pk;
      } else {
        bf16* dst = (zmode == 0) ? Qo : Ko;
        int h = col >> 6, d = col & 63;
#pragma unroll
        for (int r = 0; r < 4; r++) {
          int row = row0 + r;
          int b = row >> 11, s = row & (SS - 1);
          dst[((size_t)(b * NHEAD + h) * SS + s) * HDIM + d] = (bf16)acc[mi][ni][r];
        }
      }
    }
  }
}

// ---------------------------------------------------------------- flash pass 1: per-row max & sumexp
__global__ __launch_bounds__(256) void attn_stats(const bf16* __restrict__ Q, const bf16* __restrict__ K,
                                                  const float* __restrict__ bias, float* __restrict__ mL,
                                                  float* __restrict__ invl) {
  int bid = blockIdx.x;
  int b = bid >> 9;
  int h = (bid >> 5) & (NHEAD - 1);
  int q0 = (bid & 31) * 64;
  int t = threadIdx.x, w = t >> 6, l = t & 63, lg = l >> 4, lr = l & 15;
  size_t hb = ((size_t)b * NHEAD + h) * SS;
  const bf16* Qh = Q + hb * HDIM;
  const bf16* Kh = K + hb * HDIM;
  const float* biasb = bias + b * SS;
  int rowl = q0 + w * 16 + lr;
  bf16x8 qf0 = *(const bf16x8*)&Qh[(size_t)rowl * HDIM + lg * 8];
  bf16x8 qf1 = *(const bf16x8*)&Qh[(size_t)rowl * HDIM + 32 + lg * 8];
  float m_run[4] = {-1e30f, -1e30f, -1e30f, -1e30f};
  float l_run[4] = {0.f, 0.f, 0.f, 0.f};
  f32x4 zero4 = {0.f, 0.f, 0.f, 0.f};

  for (int k0 = 0; k0 < SS; k0 += 64) {
    f32x4 acc[4];
    float bcol[4];
#pragma unroll
    for (int ni = 0; ni < 4; ni++) {
      acc[ni] = zero4;
      int colk = k0 + ni * 16 + lr;
      bf16x8 kf0 = *(const bf16x8*)&Kh[(size_t)colk * HDIM + lg * 8];
      bf16x8 kf1 = *(const bf16x8*)&Kh[(size_t)colk * HDIM + 32 + lg * 8];
      acc[ni] = MFMA16(qf0, kf0, acc[ni]);
      acc[ni] = MFMA16(qf1, kf1, acc[ni]);
      bcol[ni] = biasb[colk];
    }
#pragma unroll
    for (int r = 0; r < 4; r++) {
      float z0 = fmaf(acc[0][r], SCALE, bcol[0]);
      float z1 = fmaf(acc[1][r], SCALE, bcol[1]);
      float z2 = fmaf(acc[2][r], SCALE, bcol[2]);
      float z3 = fmaf(acc[3][r], SCALE, bcol[3]);
      float mx = fmaxf(fmaxf(z0, z1), fmaxf(z2, z3));
#pragma unroll
      for (int off = 1; off < 16; off <<= 1) mx = fmaxf(mx, __shfl_xor(mx, off));
      float mn = fmaxf(m_run[r], mx);
      float ssum = __builtin_amdgcn_exp2f((z0 - mn) * LOG2E) + __builtin_amdgcn_exp2f((z1 - mn) * LOG2E) +
                   __builtin_amdgcn_exp2f((z2 - mn) * LOG2E) + __builtin_amdgcn_exp2f((z3 - mn) * LOG2E);
#pragma unroll
      for (int off = 1; off < 16; off <<= 1) ssum += __shfl_xor(ssum, off);
      l_run[r] = l_run[r] * __builtin_amdgcn_exp2f((m_run[r] - mn) * LOG2E) + ssum;
      m_run[r] = mn;
    }
  }
  if (lr == 0) {
#pragma unroll
    for (int r = 0; r < 4; r++) {
      int row = q0 + w * 16 + lg * 4 + r;
      mL[hb + row]   = m_run[r] * LOG2E;
      invl[hb + row] = 1.0f / l_run[r];
    }
  }
}

// ---------------------------------------------------------------- pass 2: probs -> mean (atomic) + PV
__global__ __launch_bounds__(256) void attn_pv(const bf16* __restrict__ Q, const bf16* __restrict__ K,
                                               const bf16* __restrict__ Vt, const float* __restrict__ bias,
                                               const float* __restrict__ mL, const float* __restrict__ invl,
                                               float* __restrict__ meanOut, bf16* __restrict__ ctx) {
  int b = blockIdx.z, h = blockIdx.y, q0 = blockIdx.x * 64;
  int t = threadIdx.x, w = t >> 6, l = t & 63, lg = l >> 4, lr = l & 15;
  size_t hb = ((size_t)b * NHEAD + h) * SS;
  const bf16* Qh = Q + hb * HDIM;
  const bf16* Kh = K + hb * HDIM;
  const bf16* Vh = Vt + ((size_t)b * NHEAD + h) * HDIM * SS;
  const float* biasb = bias + b * SS;
  __shared__ __align__(16) bf16 lp[4][16][72];  // per-wave P patch, padded: 144B row stride
  int rowl = q0 + w * 16 + lr;
  bf16x8 qf0 = *(const bf16x8*)&Qh[(size_t)rowl * HDIM + lg * 8];
  bf16x8 qf1 = *(const bf16x8*)&Qh[(size_t)rowl * HDIM + 32 + lg * 8];
  float mrow[4], ilrow[4];
#pragma unroll
  for (int r = 0; r < 4; r++) {
    int row = q0 + w * 16 + lg * 4 + r;
    mrow[r]  = mL[hb + row];
    ilrow[r] = invl[hb + row];
  }
  f32x4 zero4 = {0.f, 0.f, 0.f, 0.f};
  f32x4 ctxa[4];
#pragma unroll
  for (int nd = 0; nd < 4; nd++) ctxa[nd] = zero4;
  float* meanB = meanOut + (size_t)b * SS * SS;

  for (int k0 = 0; k0 < SS; k0 += 64) {
    f32x4 acc[4];
#pragma unroll
    for (int ni = 0; ni < 4; ni++) {
      acc[ni] = zero4;
      int colk = k0 + ni * 16 + lr;
      bf16x8 kf0 = *(const bf16x8*)&Kh[(size_t)colk * HDIM + lg * 8];
      bf16x8 kf1 = *(const bf16x8*)&Kh[(size_t)colk * HDIM + 32 + lg * 8];
      acc[ni] = MFMA16(qf0, kf0, acc[ni]);
      acc[ni] = MFMA16(qf1, kf1, acc[ni]);
    }
#pragma unroll
    for (int ni = 0; ni < 4; ni++) {
      float bcol = biasb[k0 + ni * 16 + lr];
#pragma unroll
      for (int r = 0; r < 4; r++) {
        float z = fmaf(acc[ni][r], SCALE, bcol);
        float p = __builtin_amdgcn_exp2f(fmaf(z, LOG2E, -mrow[r])) * ilrow[r];
        unsafeAtomicAdd(&meanB[(size_t)(q0 + w * 16 + lg * 4 + r) * SS + k0 + ni * 16 + lr],
                        p * (1.0f / NHEAD));
        lp[w][lg * 4 + r][ni * 16 + lr] = (bf16)p;
      }
    }
#pragma unroll
    for (int kk = 0; kk < 2; kk++) {
      bf16x8 pa = *(const bf16x8*)&lp[w][lr][kk * 32 + lg * 8];
#pragma unroll
      for (int nd = 0; nd < 4; nd++) {
        bf16x8 vf = *(const bf16x8*)&Vh[(size_t)(nd * 16 + lr) * SS + k0 + kk * 32 + lg * 8];
        ctxa[nd] = MFMA16(pa, vf, ctxa[nd]);
      }
    }
  }
#pragma unroll
  for (int nd = 0; nd < 4; nd++) {
#pragma unroll
    for (int r = 0; r < 4; r++) {
      int row = q0 + w * 16 + lg * 4 + r;
      ctx[(size_t)(b * SS + row) * HH + h * HDIM + nd * 16 + lr] = (bf16)ctxa[nd][r];
    }
  }
}

// ---------------------------------------------------------------- launch
extern "C" void kernel_launch(void* const* d_in, const int* in_sizes, int n_in,
                              void* d_out, int out_size, void* d_ws, size_t ws_size,
                              hipStream_t stream) {
  const float* query  = (const float*)d_in[0];
  const float* key_in = (const float*)d_in[1];
  const float* value  = (const float*)d_in[2];
  const int*   mask   = (const int*)d_in[3];
  const float* Wq     = (const float*)d_in[4];
  const float* Wk     = (const float*)d_in[5];
  const float* Wv     = (const float*)d_in[6];
  const float* Wo     = (const float*)d_in[7];

  // ws layout (bytes), total ~56.5 MB:
  // [0)        Xq bf16 (8388608)   -- reused as ctx after projections
  // [8388608)  Xk bf16
  // [16777216) Xv bf16
  // [25165824) Wt bf16 x4 (8388608)
  // [33554432) Q  bf16 (B,NH,S,HD)
  // [41943040) K  bf16 (B,NH,S,HD)
  // [50331648) Vt bf16 (B,NH,HD,S)
  // [58720256) mL f32 (262144)
  // [58982400) invl f32 (262144)
  // [59244544) bias f32 (16384)
  char* ws = (char*)d_ws;
  bf16*  Xb    = (bf16*)(ws);
  bf16*  Wt    = (bf16*)(ws + 25165824);
  bf16*  Qb    = (bf16*)(ws + 33554432);
  bf16*  Kb    = (bf16*)(ws + 41943040);
  bf16*  Vtb   = (bf16*)(ws + 50331648);
  float* mLb   = (float*)(ws + 58720256);
  float* invlb = (float*)(ws + 58982400);
  float* biasb = (float*)(ws + 59244544);
  bf16*  ctxb  = Xb;  // Xq dead after projections

  float* outF  = (float*)d_out;
  float* meanF = outF + (size_t)BB * SS * HH;  // second output: (B,S,S)

  cvt_in<<<4096, 256, 0, stream>>>(query, key_in, value, mask,
                                   Xb, Xb + 4194304, Xb + 8388608, biasb);
  cvt_wt<<<dim3(32, 32, 4), dim3(32, 8), 0, stream>>>(Wq, Wk, Wv, Wo, Wt);
  gemm128<<<dim3(8, 32, 3), 256, 0, stream>>>(Xb, Wt, Qb, Kb, Vtb, nullptr, -1);
  attn_stats<<<1024, 256, 0, stream>>>(Qb, Kb, biasb, mLb, invlb);
  hipMemsetAsync(meanF, 0, (size_t)BB * SS * SS * sizeof(float), stream);
  attn_pv<<<dim3(32, 16, 2), 256, 0, stream>>>(Qb, Kb, Vtb, biasb, mLb, invlb, meanF, ctxb);
  gemm128<<<dim3(8, 32, 1), 256, 0, stream>>>(ctxb, Wt + 3 * (size_t)HH * HH,
                                              nullptr, nullptr, nullptr, outF, 3);
}

// Round 2
// 582.247 us; speedup vs baseline: 1.1078x; 1.1078x over previous
//
#include <hip/hip_runtime.h>
#include <stdint.h>

#define BB 2
#define SS 2048
#define HH 1024
#define NHEAD 16
#define HDIM 64

constexpr int   BSROWS = BB * SS;   // 4096
constexpr float SCALE  = 0.125f;    // 1/sqrt(64)
constexpr float LOG2E  = 1.4426950408889634f;

typedef __bf16 bf16;
typedef __attribute__((ext_vector_type(8))) __bf16 bf16x8;
typedef __attribute__((ext_vector_type(4))) __bf16 bf16x4;
typedef __attribute__((ext_vector_type(4))) float  f32x4;

#define MFMA16(a, b, c) __builtin_amdgcn_mfma_f32_16x16x32_bf16((a), (b), (c), 0, 0, 0)

__device__ __forceinline__ void gload_lds16(const void* g, void* l) {
  __builtin_amdgcn_global_load_lds((const __attribute__((address_space(1))) void*)g,
                                   (__attribute__((address_space(3))) void*)l, 16, 0, 0);
}

// ---------------------------------------------------------------- convert inputs
__global__ __launch_bounds__(256) void cvt_in(const float* __restrict__ q, const float* __restrict__ k,
                                              const float* __restrict__ v, const int* __restrict__ mask,
                                              bf16* __restrict__ xq, bf16* __restrict__ xk,
                                              bf16* __restrict__ xv, float* __restrict__ bias) {
  int i = blockIdx.x * 256 + threadIdx.x;
  int e = i * 4;
  f32x4 a = *(const f32x4*)(q + e);
  f32x4 b = *(const f32x4*)(k + e);
  f32x4 c = *(const f32x4*)(v + e);
  *(bf16x4*)(xq + e) = __builtin_convertvector(a, bf16x4);
  *(bf16x4*)(xk + e) = __builtin_convertvector(b, bf16x4);
  *(bf16x4*)(xv + e) = __builtin_convertvector(c, bf16x4);
  if (i < BB * SS) bias[i] = mask[i] ? 0.0f : -1e9f;
}

// ---------------------------------------------------------------- transpose + cast weights: Wt[n][k] = W[k][n]
__global__ __launch_bounds__(256) void cvt_wt(const float* __restrict__ Wq, const float* __restrict__ Wk,
                                              const float* __restrict__ Wv, const float* __restrict__ Wo,
                                              bf16* __restrict__ Wt) {
  __shared__ float tile[32][33];
  int z = blockIdx.z;
  const float* W = (z == 0) ? Wq : (z == 1) ? Wk : (z == 2) ? Wv : Wo;
  bf16* out = Wt + (size_t)z * HH * HH;
  int bx = blockIdx.x * 32, by = blockIdx.y * 32;
  int tx = threadIdx.x, ty = threadIdx.y;
#pragma unroll
  for (int j = 0; j < 32; j += 8)
    tile[ty + j][tx] = W[(size_t)(by + ty + j) * HH + bx + tx];
  __syncthreads();
#pragma unroll
  for (int j = 0; j < 32; j += 8)
    out[(size_t)(bx + ty + j) * HH + by + tx] = (bf16)tile[tx][ty + j];
}

// ---------------------------------------------------------------- 128x128 bf16 GEMM (m97 structure)
// mode <0: blockIdx.z selects projection (0:Q, 1:K, 2:V-transposed); mode==3: f32 row-major out.
__global__ __launch_bounds__(256) void gemm128(const bf16* __restrict__ Abase, const bf16* __restrict__ Btbase,
                                               bf16* __restrict__ Qo, bf16* __restrict__ Ko,
                                               bf16* __restrict__ Vto, float* __restrict__ outF, int mode) {
  int zmode = (mode < 0) ? (int)blockIdx.z : mode;
  const bf16* A  = Abase  + (mode < 0 ? (size_t)blockIdx.z * BSROWS * HH : 0);
  const bf16* Bt = Btbase + (mode < 0 ? (size_t)blockIdx.z * HH * HH : 0);

  __shared__ __align__(16) bf16 lA[128 * 32];
  __shared__ __align__(16) bf16 lB[128 * 32];

  int t = threadIdx.x;
  int w = t >> 6, l = t & 63, lg = l >> 4, lr = l & 15;
  int m0 = blockIdx.y * 128, n0 = blockIdx.x * 128;
  int wr = (w >> 1) * 64, wc = (w & 1) * 64;

  f32x4 zero4 = {0.f, 0.f, 0.f, 0.f};
  f32x4 acc[4][4];
#pragma unroll
  for (int i = 0; i < 4; i++)
#pragma unroll
    for (int j = 0; j < 4; j++) acc[i][j] = zero4;

  for (int k0 = 0; k0 < HH; k0 += 32) {
#pragma unroll
    for (int i = 0; i < 2; i++) {
      int idx = i * 256 + t;
      gload_lds16(A  + (size_t)(m0 + (idx >> 2)) * HH + k0 + (idx & 3) * 8, &lA[(i * 256 + w * 64) * 8]);
      gload_lds16(Bt + (size_t)(n0 + (idx >> 2)) * HH + k0 + (idx & 3) * 8, &lB[(i * 256 + w * 64) * 8]);
    }
    __syncthreads();
    bf16x8 af[4], bq[4];
#pragma unroll
    for (int mi = 0; mi < 4; mi++) af[mi] = *(const bf16x8*)&lA[(wr + mi * 16 + lr) * 32 + lg * 8];
#pragma unroll
    for (int ni = 0; ni < 4; ni++) bq[ni] = *(const bf16x8*)&lB[(wc + ni * 16 + lr) * 32 + lg * 8];
#pragma unroll
    for (int mi = 0; mi < 4; mi++)
#pragma unroll
      for (int ni = 0; ni < 4; ni++)
        acc[mi][ni] = MFMA16(af[mi], bq[ni], acc[mi][ni]);
    __syncthreads();
  }

#pragma unroll
  for (int mi = 0; mi < 4; mi++) {
    int row0 = m0 + wr + mi * 16 + lg * 4;
#pragma unroll
    for (int ni = 0; ni < 4; ni++) {
      int col = n0 + wc + ni * 16 + lr;
      if (zmode == 3) {
#pragma unroll
        for (int r = 0; r < 4; r++) outF[(size_t)(row0 + r) * HH + col] = acc[mi][ni][r];
      } else if (zmode == 2) {
        int b = row0 >> 11, s0 = row0 & (SS - 1);
        int h = col >> 6, d = col & 63;
        bf16x4 pk;
#pragma unroll
        for (int r = 0; r < 4; r++) pk[r] = (bf16)acc[mi][ni][r];
        *(bf16x4*)&Vto[((size_t)(b * NHEAD + h) * HDIM + d) * SS + s0] = pk;
      } else {
        bf16* dst = (zmode == 0) ? Qo : Ko;
        int h = col >> 6, d = col & 63;
#pragma unroll
        for (int r = 0; r < 4; r++) {
          int row = row0 + r;
          int b = row >> 11, s = row & (SS - 1);
          dst[((size_t)(b * NHEAD + h) * SS + s) * HDIM + d] = (bf16)acc[mi][ni][r];
        }
      }
    }
  }
}

// ---------------------------------------------------------------- flash pass 1: per-row max & sumexp
__global__ __launch_bounds__(256) void attn_stats(const bf16* __restrict__ Q, const bf16* __restrict__ K,
                                                  const float* __restrict__ bias, float* __restrict__ mL,
                                                  float* __restrict__ invl) {
  int bid = blockIdx.x;
  int b = bid >> 9;
  int h = (bid >> 5) & (NHEAD - 1);
  int q0 = (bid & 31) * 64;
  int t = threadIdx.x, w = t >> 6, l = t & 63, lg = l >> 4, lr = l & 15;
  size_t hb = ((size_t)b * NHEAD + h) * SS;
  const bf16* Qh = Q + hb * HDIM;
  const bf16* Kh = K + hb * HDIM;
  const float* biasb = bias + b * SS;
  int rowl = q0 + w * 16 + lr;
  bf16x8 qf0 = *(const bf16x8*)&Qh[(size_t)rowl * HDIM + lg * 8];
  bf16x8 qf1 = *(const bf16x8*)&Qh[(size_t)rowl * HDIM + 32 + lg * 8];
  float m_run[4] = {-1e30f, -1e30f, -1e30f, -1e30f};
  float l_run[4] = {0.f, 0.f, 0.f, 0.f};
  f32x4 zero4 = {0.f, 0.f, 0.f, 0.f};

  for (int k0 = 0; k0 < SS; k0 += 64) {
    f32x4 acc[4];
    float bcol[4];
#pragma unroll
    for (int ni = 0; ni < 4; ni++) {
      acc[ni] = zero4;
      int colk = k0 + ni * 16 + lr;
      bf16x8 kf0 = *(const bf16x8*)&Kh[(size_t)colk * HDIM + lg * 8];
      bf16x8 kf1 = *(const bf16x8*)&Kh[(size_t)colk * HDIM + 32 + lg * 8];
      acc[ni] = MFMA16(qf0, kf0, acc[ni]);
      acc[ni] = MFMA16(qf1, kf1, acc[ni]);
      bcol[ni] = biasb[colk];
    }
#pragma unroll
    for (int r = 0; r < 4; r++) {
      float z0 = fmaf(acc[0][r], SCALE, bcol[0]);
      float z1 = fmaf(acc[1][r], SCALE, bcol[1]);
      float z2 = fmaf(acc[2][r], SCALE, bcol[2]);
      float z3 = fmaf(acc[3][r], SCALE, bcol[3]);
      float mx = fmaxf(fmaxf(z0, z1), fmaxf(z2, z3));
#pragma unroll
      for (int off = 1; off < 16; off <<= 1) mx = fmaxf(mx, __shfl_xor(mx, off));
      float mn = fmaxf(m_run[r], mx);
      float ssum = __builtin_amdgcn_exp2f((z0 - mn) * LOG2E) + __builtin_amdgcn_exp2f((z1 - mn) * LOG2E) +
                   __builtin_amdgcn_exp2f((z2 - mn) * LOG2E) + __builtin_amdgcn_exp2f((z3 - mn) * LOG2E);
#pragma unroll
      for (int off = 1; off < 16; off <<= 1) ssum += __shfl_xor(ssum, off);
      l_run[r] = l_run[r] * __builtin_amdgcn_exp2f((m_run[r] - mn) * LOG2E) + ssum;
      m_run[r] = mn;
    }
  }
  if (lr == 0) {
#pragma unroll
    for (int r = 0; r < 4; r++) {
      int row = q0 + w * 16 + lg * 4 + r;
      mL[hb + row]   = m_run[r] * LOG2E;
      invl[hb + row] = 1.0f / l_run[r];
    }
  }
}

// ---------------------------------------------------------------- head-summed mean: one block owns a 64x256 tile
__global__ __launch_bounds__(256) void attn_mean(const bf16* __restrict__ Q, const bf16* __restrict__ K,
                                                 const float* __restrict__ bias, const float* __restrict__ mL,
                                                 const float* __restrict__ invl, float* __restrict__ meanOut) {
  int q0 = blockIdx.x * 64, kc0 = blockIdx.y * 256, b = blockIdx.z;
  int t = threadIdx.x, w = t >> 6, l = t & 63, lg = l >> 4, lr = l & 15;
  const float* biasb = bias + b * SS;
  int rowl = q0 + w * 16 + lr;       // A-fragment row for this lane
  int rowo = q0 + w * 16 + lg * 4;   // C-fragment row base for this lane

  float bcol[4][4];
#pragma unroll
  for (int ks = 0; ks < 4; ks++)
#pragma unroll
    for (int ni = 0; ni < 4; ni++) bcol[ks][ni] = biasb[kc0 + ks * 64 + ni * 16 + lr];

  float macc[4][4][4];
#pragma unroll
  for (int ks = 0; ks < 4; ks++)
#pragma unroll
    for (int ni = 0; ni < 4; ni++)
#pragma unroll
      for (int r = 0; r < 4; r++) macc[ks][ni][r] = 0.f;

  f32x4 zero4 = {0.f, 0.f, 0.f, 0.f};
  for (int h = 0; h < NHEAD; h++) {
    size_t hb = ((size_t)b * NHEAD + h) * SS;
    const bf16* Qh = Q + hb * HDIM;
    const bf16* Kh = K + hb * HDIM;
    bf16x8 qf0 = *(const bf16x8*)&Qh[(size_t)rowl * HDIM + lg * 8];
    bf16x8 qf1 = *(const bf16x8*)&Qh[(size_t)rowl * HDIM + 32 + lg * 8];
    float mrow[4], ilrow[4];
#pragma unroll
    for (int r = 0; r < 4; r++) {
      mrow[r]  = mL[hb + rowo + r];
      ilrow[r] = invl[hb + rowo + r] * (1.0f / NHEAD);
    }
#pragma unroll
    for (int ks = 0; ks < 4; ks++) {
      int k0 = kc0 + ks * 64;
      f32x4 acc[4];
#pragma unroll
      for (int ni = 0; ni < 4; ni++) {
        acc[ni] = zero4;
        int colk = k0 + ni * 16 + lr;
        bf16x8 kf0 = *(const bf16x8*)&Kh[(size_t)colk * HDIM + lg * 8];
        bf16x8 kf1 = *(const bf16x8*)&Kh[(size_t)colk * HDIM + 32 + lg * 8];
        acc[ni] = MFMA16(qf0, kf0, acc[ni]);
        acc[ni] = MFMA16(qf1, kf1, acc[ni]);
      }
#pragma unroll
      for (int ni = 0; ni < 4; ni++)
#pragma unroll
        for (int r = 0; r < 4; r++) {
          float z = fmaf(acc[ni][r], SCALE, bcol[ks][ni]);
          macc[ks][ni][r] += __builtin_amdgcn_exp2f(fmaf(z, LOG2E, -mrow[r])) * ilrow[r];
        }
    }
  }
  float* meanB = meanOut + (size_t)b * SS * SS;
#pragma unroll
  for (int ks = 0; ks < 4; ks++)
#pragma unroll
    for (int ni = 0; ni < 4; ni++)
#pragma unroll
      for (int r = 0; r < 4; r++)
        meanB[(size_t)(rowo + r) * SS + kc0 + ks * 64 + ni * 16 + lr] = macc[ks][ni][r];
}

// ---------------------------------------------------------------- pass 2: probs -> PV only (no atomics)
__global__ __launch_bounds__(256) void attn_pv(const bf16* __restrict__ Q, const bf16* __restrict__ K,
                                               const bf16* __restrict__ Vt, const float* __restrict__ bias,
                                               const float* __restrict__ mL, const float* __restrict__ invl,
                                               bf16* __restrict__ ctx) {
  int b = blockIdx.z, h = blockIdx.y, q0 = blockIdx.x * 64;
  int t = threadIdx.x, w = t >> 6, l = t & 63, lg = l >> 4, lr = l & 15;
  size_t hb = ((size_t)b * NHEAD + h) * SS;
  const bf16* Qh = Q + hb * HDIM;
  const bf16* Kh = K + hb * HDIM;
  const bf16* Vh = Vt + ((size_t)b * NHEAD + h) * HDIM * SS;
  const float* biasb = bias + b * SS;
  __shared__ __align__(16) bf16 lp[4][16][72];  // per-wave P patch, padded: 144B row stride
  int rowl = q0 + w * 16 + lr;
  bf16x8 qf0 = *(const bf16x8*)&Qh[(size_t)rowl * HDIM + lg * 8];
  bf16x8 qf1 = *(const bf16x8*)&Qh[(size_t)rowl * HDIM + 32 + lg * 8];
  float mrow[4], ilrow[4];
#pragma unroll
  for (int r = 0; r < 4; r++) {
    int row = q0 + w * 16 + lg * 4 + r;
    mrow[r]  = mL[hb + row];
    ilrow[r] = invl[hb + row];
  }
  f32x4 zero4 = {0.f, 0.f, 0.f, 0.f};
  f32x4 ctxa[4];
#pragma unroll
  for (int nd = 0; nd < 4; nd++) ctxa[nd] = zero4;

  for (int k0 = 0; k0 < SS; k0 += 64) {
    f32x4 acc[4];
#pragma unroll
    for (int ni = 0; ni < 4; ni++) {
      acc[ni] = zero4;
      int colk = k0 + ni * 16 + lr;
      bf16x8 kf0 = *(const bf16x8*)&Kh[(size_t)colk * HDIM + lg * 8];
      bf16x8 kf1 = *(const bf16x8*)&Kh[(size_t)colk * HDIM + 32 + lg * 8];
      acc[ni] = MFMA16(qf0, kf0, acc[ni]);
      acc[ni] = MFMA16(qf1, kf1, acc[ni]);
    }
#pragma unroll
    for (int ni = 0; ni < 4; ni++) {
      float bcol = biasb[k0 + ni * 16 + lr];
#pragma unroll
      for (int r = 0; r < 4; r++) {
        float z = fmaf(acc[ni][r], SCALE, bcol);
        float p = __builtin_amdgcn_exp2f(fmaf(z, LOG2E, -mrow[r])) * ilrow[r];
        lp[w][lg * 4 + r][ni * 16 + lr] = (bf16)p;
      }
    }
#pragma unroll
    for (int kk = 0; kk < 2; kk++) {
      bf16x8 pa = *(const bf16x8*)&lp[w][lr][kk * 32 + lg * 8];
#pragma unroll
      for (int nd = 0; nd < 4; nd++) {
        bf16x8 vf = *(const bf16x8*)&Vh[(size_t)(nd * 16 + lr) * SS + k0 + kk * 32 + lg * 8];
        ctxa[nd] = MFMA16(pa, vf, ctxa[nd]);
      }
    }
  }
#pragma unroll
  for (int nd = 0; nd < 4; nd++) {
#pragma unroll
    for (int r = 0; r < 4; r++) {
      int row = q0 + w * 16 + lg * 4 + r;
      ctx[(size_t)(b * SS + row) * HH + h * HDIM + nd * 16 + lr] = (bf16)ctxa[nd][r];
    }
  }
}

// ---------------------------------------------------------------- launch
extern "C" void kernel_launch(void* const* d_in, const int* in_sizes, int n_in,
                              void* d_out, int out_size, void* d_ws, size_t ws_size,
                              hipStream_t stream) {
  const float* query  = (const float*)d_in[0];
  const float* key_in = (const float*)d_in[1];
  const float* value  = (const float*)d_in[2];
  const int*   mask   = (const int*)d_in[3];
  const float* Wq     = (const float*)d_in[4];
  const float* Wk     = (const float*)d_in[5];
  const float* Wv     = (const float*)d_in[6];
  const float* Wo     = (const float*)d_in[7];

  char* ws = (char*)d_ws;
  bf16*  Xb    = (bf16*)(ws);
  bf16*  Wt    = (bf16*)(ws + 25165824);
  bf16*  Qb    = (bf16*)(ws + 33554432);
  bf16*  Kb    = (bf16*)(ws + 41943040);
  bf16*  Vtb   = (bf16*)(ws + 50331648);
  float* mLb   = (float*)(ws + 58720256);
  float* invlb = (float*)(ws + 58982400);
  float* biasb = (float*)(ws + 59244544);
  bf16*  ctxb  = Xb;  // Xq dead after projections

  float* outF  = (float*)d_out;
  float* meanF = outF + (size_t)BB * SS * HH;  // second output: (B,S,S)

  cvt_in<<<4096, 256, 0, stream>>>(query, key_in, value, mask,
                                   Xb, Xb + 4194304, Xb + 8388608, biasb);
  cvt_wt<<<dim3(32, 32, 4), dim3(32, 8), 0, stream>>>(Wq, Wk, Wv, Wo, Wt);
  gemm128<<<dim3(8, 32, 3), 256, 0, stream>>>(Xb, Wt, Qb, Kb, Vtb, nullptr, -1);
  attn_stats<<<1024, 256, 0, stream>>>(Qb, Kb, biasb, mLb, invlb);
  attn_mean<<<dim3(32, 8, 2), 256, 0, stream>>>(Qb, Kb, biasb, mLb, invlb, meanF);
  attn_pv<<<dim3(32, 16, 2), 256, 0, stream>>>(Qb, Kb, Vtb, biasb, mLb, invlb, ctxb);
  gemm128<<<dim3(8, 32, 1), 256, 0, stream>>>(ctxb, Wt + 3 * (size_t)HH * HH,
                                              nullptr, nullptr, nullptr, outF, 3);
}

// Round 3
// 279.155 us; speedup vs baseline: 2.3107x; 2.0857x over previous
//
#include <hip/hip_runtime.h>
#include <stdint.h>

#define BB 2
#define SS 2048
#define HH 1024
#define NHEAD 16
#define HDIM 64

constexpr int   BSROWS = BB * SS;   // 4096
constexpr float SCALE  = 0.125f;    // 1/sqrt(64)
constexpr float LOG2E  = 1.4426950408889634f;
constexpr float SL     = SCALE * LOG2E;

typedef __bf16 bf16;
typedef __attribute__((ext_vector_type(8))) __bf16 bf16x8;
typedef __attribute__((ext_vector_type(4))) __bf16 bf16x4;
typedef __attribute__((ext_vector_type(4))) float  f32x4;

#define MFMA16(a, b, c) __builtin_amdgcn_mfma_f32_16x16x32_bf16((a), (b), (c), 0, 0, 0)

__device__ __forceinline__ void gload_lds16(const void* g, void* l) {
  __builtin_amdgcn_global_load_lds((const __attribute__((address_space(1))) void*)g,
                                   (__attribute__((address_space(3))) void*)l, 16, 0, 0);
}

// ---------------------------------------------------------------- convert inputs
__global__ __launch_bounds__(256) void cvt_in(const float* __restrict__ q, const float* __restrict__ k,
                                              const float* __restrict__ v, const int* __restrict__ mask,
                                              bf16* __restrict__ xq, bf16* __restrict__ xk,
                                              bf16* __restrict__ xv, float* __restrict__ bias) {
  int i = blockIdx.x * 256 + threadIdx.x;
  int e = i * 4;
  f32x4 a = *(const f32x4*)(q + e);
  f32x4 b = *(const f32x4*)(k + e);
  f32x4 c = *(const f32x4*)(v + e);
  *(bf16x4*)(xq + e) = __builtin_convertvector(a, bf16x4);
  *(bf16x4*)(xk + e) = __builtin_convertvector(b, bf16x4);
  *(bf16x4*)(xv + e) = __builtin_convertvector(c, bf16x4);
  if (i < BB * SS) bias[i] = mask[i] ? 0.0f : -1e9f;
}

// ---------------------------------------------------------------- transpose + cast weights: Wt[n][k] = W[k][n]
__global__ __launch_bounds__(256) void cvt_wt(const float* __restrict__ Wq, const float* __restrict__ Wk,
                                              const float* __restrict__ Wv, const float* __restrict__ Wo,
                                              bf16* __restrict__ Wt) {
  __shared__ float tile[32][33];
  int z = blockIdx.z;
  const float* W = (z == 0) ? Wq : (z == 1) ? Wk : (z == 2) ? Wv : Wo;
  bf16* out = Wt + (size_t)z * HH * HH;
  int bx = blockIdx.x * 32, by = blockIdx.y * 32;
  int tx = threadIdx.x, ty = threadIdx.y;
#pragma unroll
  for (int j = 0; j < 32; j += 8)
    tile[ty + j][tx] = W[(size_t)(by + ty + j) * HH + bx + tx];
  __syncthreads();
#pragma unroll
  for (int j = 0; j < 32; j += 8)
    out[(size_t)(bx + ty + j) * HH + by + tx] = (bf16)tile[tx][ty + j];
}

// ---------------------------------------------------------------- 128x128 bf16 GEMM (m97 structure)
__global__ __launch_bounds__(256) void gemm128(const bf16* __restrict__ Abase, const bf16* __restrict__ Btbase,
                                               bf16* __restrict__ Qo, bf16* __restrict__ Ko,
                                               bf16* __restrict__ Vto, float* __restrict__ outF, int mode) {
  int zmode = (mode < 0) ? (int)blockIdx.z : mode;
  const bf16* A  = Abase  + (mode < 0 ? (size_t)blockIdx.z * BSROWS * HH : 0);
  const bf16* Bt = Btbase + (mode < 0 ? (size_t)blockIdx.z * HH * HH : 0);

  __shared__ __align__(16) bf16 lA[128 * 32];
  __shared__ __align__(16) bf16 lB[128 * 32];

  int t = threadIdx.x;
  int w = t >> 6, l = t & 63, lg = l >> 4, lr = l & 15;
  int m0 = blockIdx.y * 128, n0 = blockIdx.x * 128;
  int wr = (w >> 1) * 64, wc = (w & 1) * 64;

  f32x4 zero4 = {0.f, 0.f, 0.f, 0.f};
  f32x4 acc[4][4];
#pragma unroll
  for (int i = 0; i < 4; i++)
#pragma unroll
    for (int j = 0; j < 4; j++) acc[i][j] = zero4;

  for (int k0 = 0; k0 < HH; k0 += 32) {
#pragma unroll
    for (int i = 0; i < 2; i++) {
      int idx = i * 256 + t;
      gload_lds16(A  + (size_t)(m0 + (idx >> 2)) * HH + k0 + (idx & 3) * 8, &lA[(i * 256 + w * 64) * 8]);
      gload_lds16(Bt + (size_t)(n0 + (idx >> 2)) * HH + k0 + (idx & 3) * 8, &lB[(i * 256 + w * 64) * 8]);
    }
    __syncthreads();
    bf16x8 af[4], bq[4];
#pragma unroll
    for (int mi = 0; mi < 4; mi++) af[mi] = *(const bf16x8*)&lA[(wr + mi * 16 + lr) * 32 + lg * 8];
#pragma unroll
    for (int ni = 0; ni < 4; ni++) bq[ni] = *(const bf16x8*)&lB[(wc + ni * 16 + lr) * 32 + lg * 8];
#pragma unroll
    for (int mi = 0; mi < 4; mi++)
#pragma unroll
      for (int ni = 0; ni < 4; ni++)
        acc[mi][ni] = MFMA16(af[mi], bq[ni], acc[mi][ni]);
    __syncthreads();
  }

#pragma unroll
  for (int mi = 0; mi < 4; mi++) {
    int row0 = m0 + wr + mi * 16 + lg * 4;
#pragma unroll
    for (int ni = 0; ni < 4; ni++) {
      int col = n0 + wc + ni * 16 + lr;
      if (zmode == 3) {
#pragma unroll
        for (int r = 0; r < 4; r++) outF[(size_t)(row0 + r) * HH + col] = acc[mi][ni][r];
      } else if (zmode == 2) {
        int b = row0 >> 11, s0 = row0 & (SS - 1);
        int h = col >> 6, d = col & 63;
        bf16x4 pk;
#pragma unroll
        for (int r = 0; r < 4; r++) pk[r] = (bf16)acc[mi][ni][r];
        *(bf16x4*)&Vto[((size_t)(b * NHEAD + h) * HDIM + d) * SS + s0] = pk;
      } else {
        bf16* dst = (zmode == 0) ? Qo : Ko;
        int h = col >> 6, d = col & 63;
#pragma unroll
        for (int r = 0; r < 4; r++) {
          int row = row0 + r;
          int b = row >> 11, s = row & (SS - 1);
          dst[((size_t)(b * NHEAD + h) * SS + s) * HDIM + d] = (bf16)acc[mi][ni][r];
        }
      }
    }
  }
}

// ---------------------------------------------------------------- online flash: QK -> softmax -> PV, writes stats
__global__ __launch_bounds__(256) void attn_pv(const bf16* __restrict__ Q, const bf16* __restrict__ K,
                                               const bf16* __restrict__ Vt, const float* __restrict__ bias,
                                               float* __restrict__ mL, float* __restrict__ invl,
                                               bf16* __restrict__ ctx) {
  int b = blockIdx.z, h = blockIdx.y, q0 = blockIdx.x * 64;
  int t = threadIdx.x, w = t >> 6, l = t & 63, lg = l >> 4, lr = l & 15;
  size_t hb = ((size_t)b * NHEAD + h) * SS;
  const bf16* Qh = Q + hb * HDIM;
  const bf16* Kh = K + hb * HDIM;
  const bf16* Vh = Vt + ((size_t)b * NHEAD + h) * HDIM * SS;
  const float* biasb = bias + b * SS;

  __shared__ __align__(16) bf16 sK[64][72];   // K tile: rows=k-col, cols=dim (padded: 2-way banks)
  __shared__ __align__(16) bf16 sV[64][72];   // V tile: rows=dim,  cols=k-col
  __shared__ __align__(16) bf16 lp[4][16][72];

  int r0 = t >> 3, c0 = (t & 7) * 8;          // staging: 2 chunks of 16B per thread per tile
  bf16x8 kreg[2], vreg[2];

  int rowl = q0 + w * 16 + lr;
  bf16x8 qf0 = *(const bf16x8*)&Qh[(size_t)rowl * HDIM + lg * 8];
  bf16x8 qf1 = *(const bf16x8*)&Qh[(size_t)rowl * HDIM + 32 + lg * 8];

  float m2[4]   = {-1e30f, -1e30f, -1e30f, -1e30f};  // running max, log2 domain
  float lsum[4] = {0.f, 0.f, 0.f, 0.f};
  f32x4 zero4 = {0.f, 0.f, 0.f, 0.f};
  f32x4 ctxa[4];
#pragma unroll
  for (int nd = 0; nd < 4; nd++) ctxa[nd] = zero4;

  // prologue: stage tile 0
#pragma unroll
  for (int i = 0; i < 2; i++) {
    int row = i * 32 + r0;
    kreg[i] = *(const bf16x8*)&Kh[(size_t)row * HDIM + c0];
    vreg[i] = *(const bf16x8*)&Vh[(size_t)row * SS + c0];
  }
#pragma unroll
  for (int i = 0; i < 2; i++) {
    int row = i * 32 + r0;
    *(bf16x8*)&sK[row][c0] = kreg[i];
    *(bf16x8*)&sV[row][c0] = vreg[i];
  }

  for (int kt = 0; kt < 32; kt++) {
    int k0 = kt * 64;
    __syncthreads();                      // staged tile visible
    if (kt < 31) {                        // issue next tile's loads early (latency hides under compute)
      int kn = k0 + 64;
#pragma unroll
      for (int i = 0; i < 2; i++) {
        int row = i * 32 + r0;
        kreg[i] = *(const bf16x8*)&Kh[(size_t)(kn + row) * HDIM + c0];
        vreg[i] = *(const bf16x8*)&Vh[(size_t)row * SS + kn + c0];
      }
    }
    // ---- QK^T from LDS
    f32x4 acc[4];
#pragma unroll
    for (int ni = 0; ni < 4; ni++) {
      bf16x8 kf0 = *(const bf16x8*)&sK[ni * 16 + lr][lg * 8];
      bf16x8 kf1 = *(const bf16x8*)&sK[ni * 16 + lr][32 + lg * 8];
      f32x4 a0 = MFMA16(qf0, kf0, zero4);
      acc[ni] = MFMA16(qf1, kf1, a0);
    }
    float b2[4];
#pragma unroll
    for (int ni = 0; ni < 4; ni++) b2[ni] = biasb[k0 + ni * 16 + lr] * LOG2E;
    // ---- online softmax (log2 domain)
    float sc[4];
#pragma unroll
    for (int r = 0; r < 4; r++) {
      float z0 = fmaf(acc[0][r], SL, b2[0]);
      float z1 = fmaf(acc[1][r], SL, b2[1]);
      float z2 = fmaf(acc[2][r], SL, b2[2]);
      float z3 = fmaf(acc[3][r], SL, b2[3]);
      float mx = fmaxf(fmaxf(z0, z1), fmaxf(z2, z3));
#pragma unroll
      for (int off = 1; off < 16; off <<= 1) mx = fmaxf(mx, __shfl_xor(mx, off));
      float mn = fmaxf(m2[r], mx);
      float p0 = __builtin_amdgcn_exp2f(z0 - mn);
      float p1 = __builtin_amdgcn_exp2f(z1 - mn);
      float p2 = __builtin_amdgcn_exp2f(z2 - mn);
      float p3 = __builtin_amdgcn_exp2f(z3 - mn);
      float ssum = (p0 + p1) + (p2 + p3);
#pragma unroll
      for (int off = 1; off < 16; off <<= 1) ssum += __shfl_xor(ssum, off);
      sc[r] = __builtin_amdgcn_exp2f(m2[r] - mn);
      lsum[r] = lsum[r] * sc[r] + ssum;
      m2[r] = mn;
      lp[w][lg * 4 + r][lr]      = (bf16)p0;
      lp[w][lg * 4 + r][16 + lr] = (bf16)p1;
      lp[w][lg * 4 + r][32 + lr] = (bf16)p2;
      lp[w][lg * 4 + r][48 + lr] = (bf16)p3;
    }
    f32x4 scv;
    scv[0] = sc[0]; scv[1] = sc[1]; scv[2] = sc[2]; scv[3] = sc[3];
#pragma unroll
    for (int nd = 0; nd < 4; nd++) ctxa[nd] *= scv;
    // ---- PV from LDS
#pragma unroll
    for (int kk = 0; kk < 2; kk++) {
      bf16x8 pa = *(const bf16x8*)&lp[w][lr][kk * 32 + lg * 8];
#pragma unroll
      for (int nd = 0; nd < 4; nd++) {
        bf16x8 vf = *(const bf16x8*)&sV[nd * 16 + lr][kk * 32 + lg * 8];
        ctxa[nd] = MFMA16(pa, vf, ctxa[nd]);
      }
    }
    __syncthreads();                      // all waves done reading this tile
    if (kt < 31) {                        // overwrite buffer for next iteration
#pragma unroll
      for (int i = 0; i < 2; i++) {
        int row = i * 32 + r0;
        *(bf16x8*)&sK[row][c0] = kreg[i];
        *(bf16x8*)&sV[row][c0] = vreg[i];
      }
    }
  }

  // epilogue: normalize, store ctx + stats
  float il[4];
#pragma unroll
  for (int r = 0; r < 4; r++) il[r] = 1.0f / lsum[r];
#pragma unroll
  for (int nd = 0; nd < 4; nd++)
#pragma unroll
    for (int r = 0; r < 4; r++) {
      int row = q0 + w * 16 + lg * 4 + r;
      ctx[(size_t)(b * SS + row) * HH + h * HDIM + nd * 16 + lr] = (bf16)(ctxa[nd][r] * il[r]);
    }
  if (lr == 0) {
#pragma unroll
    for (int r = 0; r < 4; r++) {
      int row = q0 + w * 16 + lg * 4 + r;
      mL[hb + row]   = m2[r];
      invl[hb + row] = il[r];
    }
  }
}

// ---------------------------------------------------------------- head-summed mean (uses pv's stats), staged K
__global__ __launch_bounds__(256) void attn_mean(const bf16* __restrict__ Q, const bf16* __restrict__ K,
                                                 const float* __restrict__ bias, const float* __restrict__ mL,
                                                 const float* __restrict__ invl, float* __restrict__ meanOut) {
  int q0 = blockIdx.x * 64, kc0 = blockIdx.y * 128, b = blockIdx.z;
  int t = threadIdx.x, w = t >> 6, l = t & 63, lg = l >> 4, lr = l & 15;
  const float* biasb = bias + b * SS;
  __shared__ __align__(16) bf16 sK[64][72];
  int r0 = t >> 3, c0 = (t & 7) * 8;
  int rowl = q0 + w * 16 + lr, rowo = q0 + w * 16 + lg * 4;

  float b2[2][4];
#pragma unroll
  for (int ks = 0; ks < 2; ks++)
#pragma unroll
    for (int ni = 0; ni < 4; ni++) b2[ks][ni] = biasb[kc0 + ks * 64 + ni * 16 + lr] * LOG2E;

  float macc[2][4][4];
#pragma unroll
  for (int ks = 0; ks < 2; ks++)
#pragma unroll
    for (int ni = 0; ni < 4; ni++)
#pragma unroll
      for (int r = 0; r < 4; r++) macc[ks][ni][r] = 0.f;

  f32x4 zero4 = {0.f, 0.f, 0.f, 0.f};
  bf16x8 kreg[2];
  // prologue: stage (h=0, ks=0)
  {
    const bf16* Kh = K + ((size_t)b * NHEAD) * SS * HDIM;
#pragma unroll
    for (int i = 0; i < 2; i++)
      kreg[i] = *(const bf16x8*)&Kh[(size_t)(kc0 + i * 32 + r0) * HDIM + c0];
#pragma unroll
    for (int i = 0; i < 2; i++)
      *(bf16x8*)&sK[i * 32 + r0][c0] = kreg[i];
  }

  for (int j = 0; j < 32; j++) {
    int h = j >> 1, ks = j & 1;
    __syncthreads();
    if (j < 31) {
      int jn = j + 1, hn = jn >> 1, kn = kc0 + (jn & 1) * 64;
      const bf16* Khn = K + ((size_t)b * NHEAD + hn) * SS * HDIM;
#pragma unroll
      for (int i = 0; i < 2; i++)
        kreg[i] = *(const bf16x8*)&Khn[(size_t)(kn + i * 32 + r0) * HDIM + c0];
    }
    size_t hb = ((size_t)b * NHEAD + h) * SS;
    const bf16* Qh = Q + hb * HDIM;
    bf16x8 qf0 = *(const bf16x8*)&Qh[(size_t)rowl * HDIM + lg * 8];
    bf16x8 qf1 = *(const bf16x8*)&Qh[(size_t)rowl * HDIM + 32 + lg * 8];
    float mrow[4], ilrow[4];
#pragma unroll
    for (int r = 0; r < 4; r++) {
      mrow[r]  = mL[hb + rowo + r];
      ilrow[r] = invl[hb + rowo + r] * (1.0f / NHEAD);
    }
    f32x4 acc[4];
#pragma unroll
    for (int ni = 0; ni < 4; ni++) {
      bf16x8 kf0 = *(const bf16x8*)&sK[ni * 16 + lr][lg * 8];
      bf16x8 kf1 = *(const bf16x8*)&sK[ni * 16 + lr][32 + lg * 8];
      f32x4 a0 = MFMA16(qf0, kf0, zero4);
      acc[ni] = MFMA16(qf1, kf1, a0);
    }
#pragma unroll
    for (int ni = 0; ni < 4; ni++)
#pragma unroll
      for (int r = 0; r < 4; r++) {
        float z2 = fmaf(acc[ni][r], SL, b2[ks][ni]);
        macc[ks][ni][r] += __builtin_amdgcn_exp2f(z2 - mrow[r]) * ilrow[r];
      }
    __syncthreads();
    if (j < 31) {
#pragma unroll
      for (int i = 0; i < 2; i++)
        *(bf16x8*)&sK[i * 32 + r0][c0] = kreg[i];
    }
  }
  float* meanB = meanOut + (size_t)b * SS * SS;
#pragma unroll
  for (int ks = 0; ks < 2; ks++)
#pragma unroll
    for (int ni = 0; ni < 4; ni++)
#pragma unroll
      for (int r = 0; r < 4; r++)
        meanB[(size_t)(rowo + r) * SS + kc0 + ks * 64 + ni * 16 + lr] = macc[ks][ni][r];
}

// ---------------------------------------------------------------- launch
extern "C" void kernel_launch(void* const* d_in, const int* in_sizes, int n_in,
                              void* d_out, int out_size, void* d_ws, size_t ws_size,
                              hipStream_t stream) {
  const float* query  = (const float*)d_in[0];
  const float* key_in = (const float*)d_in[1];
  const float* value  = (const float*)d_in[2];
  const int*   mask   = (const int*)d_in[3];
  const float* Wq     = (const float*)d_in[4];
  const float* Wk     = (const float*)d_in[5];
  const float* Wv     = (const float*)d_in[6];
  const float* Wo     = (const float*)d_in[7];

  char* ws = (char*)d_ws;
  bf16*  Xb    = (bf16*)(ws);
  bf16*  Wt    = (bf16*)(ws + 25165824);
  bf16*  Qb    = (bf16*)(ws + 33554432);
  bf16*  Kb    = (bf16*)(ws + 41943040);
  bf16*  Vtb   = (bf16*)(ws + 50331648);
  float* mLb   = (float*)(ws + 58720256);
  float* invlb = (float*)(ws + 58982400);
  float* biasb = (float*)(ws + 59244544);
  bf16*  ctxb  = Xb;  // Xq dead after projections

  float* outF  = (float*)d_out;
  float* meanF = outF + (size_t)BB * SS * HH;  // second output: (B,S,S)

  cvt_in<<<4096, 256, 0, stream>>>(query, key_in, value, mask,
                                   Xb, Xb + 4194304, Xb + 8388608, biasb);
  cvt_wt<<<dim3(32, 32, 4), dim3(32, 8), 0, stream>>>(Wq, Wk, Wv, Wo, Wt);
  gemm128<<<dim3(8, 32, 3), 256, 0, stream>>>(Xb, Wt, Qb, Kb, Vtb, nullptr, -1);
  attn_pv<<<dim3(32, 16, 2), 256, 0, stream>>>(Qb, Kb, Vtb, biasb, mLb, invlb, ctxb);
  attn_mean<<<dim3(32, 16, 2), 256, 0, stream>>>(Qb, Kb, biasb, mLb, invlb, meanF);
  gemm128<<<dim3(8, 32, 1), 256, 0, stream>>>(ctxb, Wt + 3 * (size_t)HH * HH,
                                              nullptr, nullptr, nullptr, outF, 3);
}

// Round 4
// 228.934 us; speedup vs baseline: 2.8175x; 1.2194x over previous
//
#include <hip/hip_runtime.h>
#include <stdint.h>

#define BB 2
#define SS 2048
#define HH 1024
#define NHEAD 16
#define HDIM 64

constexpr int   BSROWS = BB * SS;   // 4096
constexpr float SCALE  = 0.125f;    // 1/sqrt(64)
constexpr float LOG2E  = 1.4426950408889634f;
constexpr float SL     = SCALE * LOG2E;

typedef __bf16 bf16;
typedef __attribute__((ext_vector_type(8))) __bf16 bf16x8;
typedef __attribute__((ext_vector_type(4))) __bf16 bf16x4;
typedef __attribute__((ext_vector_type(4))) float  f32x4;

#define MFMA16(a, b, c) __builtin_amdgcn_mfma_f32_16x16x32_bf16((a), (b), (c), 0, 0, 0)

__device__ __forceinline__ void gload_lds16(const void* g, void* l) {
  __builtin_amdgcn_global_load_lds((const __attribute__((address_space(1))) void*)g,
                                   (__attribute__((address_space(3))) void*)l, 16, 0, 0);
}

// ---------------------------------------------------------------- convert inputs (bias pre-scaled by LOG2E)
__global__ __launch_bounds__(256) void cvt_in(const float* __restrict__ q, const float* __restrict__ k,
                                              const float* __restrict__ v, const int* __restrict__ mask,
                                              bf16* __restrict__ xq, bf16* __restrict__ xk,
                                              bf16* __restrict__ xv, float* __restrict__ bias2) {
  int i = blockIdx.x * 256 + threadIdx.x;
  int e = i * 4;
  f32x4 a = *(const f32x4*)(q + e);
  f32x4 b = *(const f32x4*)(k + e);
  f32x4 c = *(const f32x4*)(v + e);
  *(bf16x4*)(xq + e) = __builtin_convertvector(a, bf16x4);
  *(bf16x4*)(xk + e) = __builtin_convertvector(b, bf16x4);
  *(bf16x4*)(xv + e) = __builtin_convertvector(c, bf16x4);
  if (i < BB * SS) bias2[i] = mask[i] ? 0.0f : -1e9f * LOG2E;
}

// ---------------------------------------------------------------- transpose + cast weights: Wt[n][k] = W[k][n]
__global__ __launch_bounds__(256) void cvt_wt(const float* __restrict__ Wq, const float* __restrict__ Wk,
                                              const float* __restrict__ Wv, const float* __restrict__ Wo,
                                              bf16* __restrict__ Wt) {
  __shared__ float tile[32][33];
  int z = blockIdx.z;
  const float* W = (z == 0) ? Wq : (z == 1) ? Wk : (z == 2) ? Wv : Wo;
  bf16* out = Wt + (size_t)z * HH * HH;
  int bx = blockIdx.x * 32, by = blockIdx.y * 32;
  int tx = threadIdx.x, ty = threadIdx.y;
#pragma unroll
  for (int j = 0; j < 32; j += 8)
    tile[ty + j][tx] = W[(size_t)(by + ty + j) * HH + bx + tx];
  __syncthreads();
#pragma unroll
  for (int j = 0; j < 32; j += 8)
    out[(size_t)(bx + ty + j) * HH + by + tx] = (bf16)tile[tx][ty + j];
}

// ---------------------------------------------------------------- 128x128 bf16 GEMM (m97 structure)
__global__ __launch_bounds__(256) void gemm128(const bf16* __restrict__ Abase, const bf16* __restrict__ Btbase,
                                               bf16* __restrict__ Qo, bf16* __restrict__ Ko,
                                               bf16* __restrict__ Vto, float* __restrict__ outF, int mode) {
  int zmode = (mode < 0) ? (int)blockIdx.z : mode;
  const bf16* A  = Abase  + (mode < 0 ? (size_t)blockIdx.z * BSROWS * HH : 0);
  const bf16* Bt = Btbase + (mode < 0 ? (size_t)blockIdx.z * HH * HH : 0);

  __shared__ __align__(16) bf16 lA[128 * 32];
  __shared__ __align__(16) bf16 lB[128 * 32];

  int t = threadIdx.x;
  int w = t >> 6, l = t & 63, lg = l >> 4, lr = l & 15;
  int m0 = blockIdx.y * 128, n0 = blockIdx.x * 128;
  int wr = (w >> 1) * 64, wc = (w & 1) * 64;

  f32x4 zero4 = {0.f, 0.f, 0.f, 0.f};
  f32x4 acc[4][4];
#pragma unroll
  for (int i = 0; i < 4; i++)
#pragma unroll
    for (int j = 0; j < 4; j++) acc[i][j] = zero4;

  for (int k0 = 0; k0 < HH; k0 += 32) {
#pragma unroll
    for (int i = 0; i < 2; i++) {
      int idx = i * 256 + t;
      gload_lds16(A  + (size_t)(m0 + (idx >> 2)) * HH + k0 + (idx & 3) * 8, &lA[(i * 256 + w * 64) * 8]);
      gload_lds16(Bt + (size_t)(n0 + (idx >> 2)) * HH + k0 + (idx & 3) * 8, &lB[(i * 256 + w * 64) * 8]);
    }
    __syncthreads();
    bf16x8 af[4], bq[4];
#pragma unroll
    for (int mi = 0; mi < 4; mi++) af[mi] = *(const bf16x8*)&lA[(wr + mi * 16 + lr) * 32 + lg * 8];
#pragma unroll
    for (int ni = 0; ni < 4; ni++) bq[ni] = *(const bf16x8*)&lB[(wc + ni * 16 + lr) * 32 + lg * 8];
#pragma unroll
    for (int mi = 0; mi < 4; mi++)
#pragma unroll
      for (int ni = 0; ni < 4; ni++)
        acc[mi][ni] = MFMA16(af[mi], bq[ni], acc[mi][ni]);
    __syncthreads();
  }

#pragma unroll
  for (int mi = 0; mi < 4; mi++) {
    int row0 = m0 + wr + mi * 16 + lg * 4;
#pragma unroll
    for (int ni = 0; ni < 4; ni++) {
      int col = n0 + wc + ni * 16 + lr;
      if (zmode == 3) {
#pragma unroll
        for (int r = 0; r < 4; r++) outF[(size_t)(row0 + r) * HH + col] = acc[mi][ni][r];
      } else if (zmode == 2) {
        int b = row0 >> 11, s0 = row0 & (SS - 1);
        int h = col >> 6, d = col & 63;
        bf16x4 pk;
#pragma unroll
        for (int r = 0; r < 4; r++) pk[r] = (bf16)acc[mi][ni][r];
        *(bf16x4*)&Vto[((size_t)(b * NHEAD + h) * HDIM + d) * SS + s0] = pk;
      } else {
        bf16* dst = (zmode == 0) ? Qo : Ko;
        int h = col >> 6, d = col & 63;
#pragma unroll
        for (int r = 0; r < 4; r++) {
          int row = row0 + r;
          int b = row >> 11, s = row & (SS - 1);
          dst[((size_t)(b * NHEAD + h) * SS + s) * HDIM + d] = (bf16)acc[mi][ni][r];
        }
      }
    }
  }
}

// ---------------------------------------------------------------- online flash, swapped QK^T (lane-local rows)
__global__ __launch_bounds__(256) void attn_pv(const bf16* __restrict__ Q, const bf16* __restrict__ K,
                                               const bf16* __restrict__ Vt, const float* __restrict__ bias2,
                                               float* __restrict__ mL, float* __restrict__ invl,
                                               bf16* __restrict__ ctx) {
  int b = blockIdx.z, h = blockIdx.y, q0 = blockIdx.x * 64;
  int t = threadIdx.x, w = t >> 6, l = t & 63, lg = l >> 4, lr = l & 15;
  size_t hb = ((size_t)b * NHEAD + h) * SS;
  const bf16* Qh = Q + hb * HDIM;
  const bf16* Kh = K + hb * HDIM;
  const bf16* Vh = Vt + ((size_t)b * NHEAD + h) * HDIM * SS;
  const float* biasb = bias2 + b * SS;

  __shared__ __align__(16) bf16 sK[64][72];   // K tile: rows=kcol, cols=dim
  __shared__ __align__(16) bf16 sV[64][72];   // V tile: rows=dim,  cols=kcol
  __shared__ __align__(16) bf16 lp[4][16][72];

  int r0 = t >> 3, c0 = (t & 7) * 8;
  bf16x8 kreg[2], vreg[2];

  int rowl = q0 + w * 16 + lr;  // this lane's q-row (for QK B-frag AND its softmax stats)
  bf16x8 qf0 = *(const bf16x8*)&Qh[(size_t)rowl * HDIM + lg * 8];
  bf16x8 qf1 = *(const bf16x8*)&Qh[(size_t)rowl * HDIM + 32 + lg * 8];

  float m2 = -1e30f, lsum = 0.f;              // stats for qrow = lr (log2 domain)
  f32x4 zero4 = {0.f, 0.f, 0.f, 0.f};
  f32x4 ctxa[4];
#pragma unroll
  for (int nd = 0; nd < 4; nd++) ctxa[nd] = zero4;

  // prologue: stage tile 0
#pragma unroll
  for (int i = 0; i < 2; i++) {
    int row = i * 32 + r0;
    kreg[i] = *(const bf16x8*)&Kh[(size_t)row * HDIM + c0];
    vreg[i] = *(const bf16x8*)&Vh[(size_t)row * SS + c0];
  }
#pragma unroll
  for (int i = 0; i < 2; i++) {
    int row = i * 32 + r0;
    *(bf16x8*)&sK[row][c0] = kreg[i];
    *(bf16x8*)&sV[row][c0] = vreg[i];
  }

  for (int kt = 0; kt < 32; kt++) {
    int k0 = kt * 64;
    __syncthreads();                      // staged tile visible
    if (kt < 31) {                        // issue next tile's loads early
      int kn = k0 + 64;
#pragma unroll
      for (int i = 0; i < 2; i++) {
        int row = i * 32 + r0;
        kreg[i] = *(const bf16x8*)&Kh[(size_t)(kn + row) * HDIM + c0];
        vreg[i] = *(const bf16x8*)&Vh[(size_t)row * SS + kn + c0];
      }
    }
    // ---- swapped QK^T: acc[ni][r] = S[kcol = ni*16+lg*4+r][qrow = lr]
    f32x4 acc[4];
#pragma unroll
    for (int ni = 0; ni < 4; ni++) {
      bf16x8 kf0 = *(const bf16x8*)&sK[ni * 16 + lr][lg * 8];
      bf16x8 kf1 = *(const bf16x8*)&sK[ni * 16 + lr][32 + lg * 8];
      f32x4 a0 = MFMA16(kf0, qf0, zero4);
      acc[ni] = MFMA16(kf1, qf1, a0);
    }
    // ---- z = s*SL + bias2 (vectorized; bias r-contiguous per lane)
    f32x4 zv[4];
#pragma unroll
    for (int ni = 0; ni < 4; ni++) {
      f32x4 bv = *(const f32x4*)&biasb[k0 + ni * 16 + lg * 4];
      zv[ni] = acc[ni] * SL + bv;
    }
    // ---- row max: 15 local + 2-shuffle butterfly over lg groups
    float mloc[4];
#pragma unroll
    for (int ni = 0; ni < 4; ni++)
      mloc[ni] = fmaxf(fmaxf(zv[ni][0], zv[ni][1]), fmaxf(zv[ni][2], zv[ni][3]));
    float mx = fmaxf(fmaxf(mloc[0], mloc[1]), fmaxf(mloc[2], mloc[3]));
    mx = fmaxf(mx, __shfl_xor(mx, 16));
    mx = fmaxf(mx, __shfl_xor(mx, 32));
    float mn = fmaxf(m2, mx);
    float sc = __builtin_amdgcn_exp2f(m2 - mn);
    m2 = mn;
    // ---- p = exp2(z - mn), sum, pack to LDS (b64 per ni)
    f32x4 pv4[4];
#pragma unroll
    for (int ni = 0; ni < 4; ni++)
#pragma unroll
      for (int r = 0; r < 4; r++) pv4[ni][r] = __builtin_amdgcn_exp2f(zv[ni][r] - mn);
    f32x4 sacc = (pv4[0] + pv4[1]) + (pv4[2] + pv4[3]);
    float ssum = (sacc[0] + sacc[1]) + (sacc[2] + sacc[3]);
    ssum += __shfl_xor(ssum, 16);
    ssum += __shfl_xor(ssum, 32);
    lsum = lsum * sc + ssum;
#pragma unroll
    for (int ni = 0; ni < 4; ni++)
      *(bf16x4*)&lp[w][lr][ni * 16 + lg * 4] = __builtin_convertvector(pv4[ni], bf16x4);
    // ---- rescale ctx (rows lg*4+r: fetch sc from owning lane)
    f32x4 scv;
#pragma unroll
    for (int r = 0; r < 4; r++) scv[r] = __shfl(sc, lg * 4 + r);
#pragma unroll
    for (int nd = 0; nd < 4; nd++) ctxa[nd] *= scv;
    // ---- PV from LDS
#pragma unroll
    for (int kk = 0; kk < 2; kk++) {
      bf16x8 pa = *(const bf16x8*)&lp[w][lr][kk * 32 + lg * 8];
#pragma unroll
      for (int nd = 0; nd < 4; nd++) {
        bf16x8 vf = *(const bf16x8*)&sV[nd * 16 + lr][kk * 32 + lg * 8];
        ctxa[nd] = MFMA16(pa, vf, ctxa[nd]);
      }
    }
    __syncthreads();                      // all waves done reading this tile
    if (kt < 31) {
#pragma unroll
      for (int i = 0; i < 2; i++) {
        int row = i * 32 + r0;
        *(bf16x8*)&sK[row][c0] = kreg[i];
        *(bf16x8*)&sV[row][c0] = vreg[i];
      }
    }
  }

  // epilogue: normalize, store ctx + stats
  float il = 1.0f / lsum;
  f32x4 ilv;
#pragma unroll
  for (int r = 0; r < 4; r++) ilv[r] = __shfl(il, lg * 4 + r);
#pragma unroll
  for (int nd = 0; nd < 4; nd++)
#pragma unroll
    for (int r = 0; r < 4; r++) {
      int row = q0 + w * 16 + lg * 4 + r;
      ctx[(size_t)(b * SS + row) * HH + h * HDIM + nd * 16 + lr] = (bf16)(ctxa[nd][r] * ilv[r]);
    }
  if (l < 16) {
    mL[hb + q0 + w * 16 + l]   = m2;
    invl[hb + q0 + w * 16 + l] = il;
  }
}

// ---------------------------------------------------------------- head-summed mean, swapped QK^T
__global__ __launch_bounds__(256) void attn_mean(const bf16* __restrict__ Q, const bf16* __restrict__ K,
                                                 const float* __restrict__ bias2, const float* __restrict__ mL,
                                                 const float* __restrict__ invl, float* __restrict__ meanOut) {
  int q0 = blockIdx.x * 64, kc0 = blockIdx.y * 128, b = blockIdx.z;
  int t = threadIdx.x, w = t >> 6, l = t & 63, lg = l >> 4, lr = l & 15;
  const float* biasb = bias2 + b * SS;
  __shared__ __align__(16) bf16 sK[64][72];
  int r0 = t >> 3, c0 = (t & 7) * 8;
  int rowl = q0 + w * 16 + lr;

  f32x4 bv2[2][4];                       // hoisted: bias doesn't depend on h
#pragma unroll
  for (int ks = 0; ks < 2; ks++)
#pragma unroll
    for (int ni = 0; ni < 4; ni++)
      bv2[ks][ni] = *(const f32x4*)&biasb[kc0 + ks * 64 + ni * 16 + lg * 4];

  f32x4 zero4 = {0.f, 0.f, 0.f, 0.f};
  f32x4 macc[2][4];
#pragma unroll
  for (int ks = 0; ks < 2; ks++)
#pragma unroll
    for (int ni = 0; ni < 4; ni++) macc[ks][ni] = zero4;

  bf16x8 kreg[2], qf0, qf1;
  float mrow = 0.f, ilr = 0.f;
  // prologue: stage (h=0, ks=0)
  {
    const bf16* Kh = K + ((size_t)b * NHEAD) * SS * HDIM;
#pragma unroll
    for (int i = 0; i < 2; i++)
      kreg[i] = *(const bf16x8*)&Kh[(size_t)(kc0 + i * 32 + r0) * HDIM + c0];
#pragma unroll
    for (int i = 0; i < 2; i++)
      *(bf16x8*)&sK[i * 32 + r0][c0] = kreg[i];
  }

  for (int j = 0; j < 32; j++) {
    int h = j >> 1, ks = j & 1;
    size_t hb = ((size_t)b * NHEAD + h) * SS;
    __syncthreads();
    if (j < 31) {
      int jn = j + 1, hn = jn >> 1, kn = kc0 + (jn & 1) * 64;
      const bf16* Khn = K + ((size_t)b * NHEAD + hn) * SS * HDIM;
#pragma unroll
      for (int i = 0; i < 2; i++)
        kreg[i] = *(const bf16x8*)&Khn[(size_t)(kn + i * 32 + r0) * HDIM + c0];
    }
    if (ks == 0) {                       // per-head: Q frags + this lane's row stats
      const bf16* Qh = Q + hb * HDIM;
      qf0 = *(const bf16x8*)&Qh[(size_t)rowl * HDIM + lg * 8];
      qf1 = *(const bf16x8*)&Qh[(size_t)rowl * HDIM + 32 + lg * 8];
      mrow = mL[hb + rowl];
      ilr  = invl[hb + rowl] * (1.0f / NHEAD);
    }
    f32x4 acc[4];
#pragma unroll
    for (int ni = 0; ni < 4; ni++) {
      bf16x8 kf0 = *(const bf16x8*)&sK[ni * 16 + lr][lg * 8];
      bf16x8 kf1 = *(const bf16x8*)&sK[ni * 16 + lr][32 + lg * 8];
      f32x4 a0 = MFMA16(kf0, qf0, zero4);
      acc[ni] = MFMA16(kf1, qf1, a0);
    }
#pragma unroll
    for (int ni = 0; ni < 4; ni++) {
      f32x4 z = acc[ni] * SL + bv2[ks][ni];
#pragma unroll
      for (int r = 0; r < 4; r++)
        macc[ks][ni][r] += __builtin_amdgcn_exp2f(z[r] - mrow) * ilr;
    }
    __syncthreads();
    if (j < 31) {
#pragma unroll
      for (int i = 0; i < 2; i++)
        *(bf16x8*)&sK[i * 32 + r0][c0] = kreg[i];
    }
  }
  float* meanB = meanOut + (size_t)b * SS * SS;
#pragma unroll
  for (int ks = 0; ks < 2; ks++)
#pragma unroll
    for (int ni = 0; ni < 4; ni++)
      *(f32x4*)&meanB[(size_t)rowl * SS + kc0 + ks * 64 + ni * 16 + lg * 4] = macc[ks][ni];
}

// ---------------------------------------------------------------- launch
extern "C" void kernel_launch(void* const* d_in, const int* in_sizes, int n_in,
                              void* d_out, int out_size, void* d_ws, size_t ws_size,
                              hipStream_t stream) {
  const float* query  = (const float*)d_in[0];
  const float* key_in = (const float*)d_in[1];
  const float* value  = (const float*)d_in[2];
  const int*   mask   = (const int*)d_in[3];
  const float* Wq     = (const float*)d_in[4];
  const float* Wk     = (const float*)d_in[5];
  const float* Wv     = (const float*)d_in[6];
  const float* Wo     = (const float*)d_in[7];

  char* ws = (char*)d_ws;
  bf16*  Xb    = (bf16*)(ws);
  bf16*  Wt    = (bf16*)(ws + 25165824);
  bf16*  Qb    = (bf16*)(ws + 33554432);
  bf16*  Kb    = (bf16*)(ws + 41943040);
  bf16*  Vtb   = (bf16*)(ws + 50331648);
  float* mLb   = (float*)(ws + 58720256);
  float* invlb = (float*)(ws + 58982400);
  float* biasb = (float*)(ws + 59244544);
  bf16*  ctxb  = Xb;  // Xq dead after projections

  float* outF  = (float*)d_out;
  float* meanF = outF + (size_t)BB * SS * HH;  // second output: (B,S,S)

  cvt_in<<<4096, 256, 0, stream>>>(query, key_in, value, mask,
                                   Xb, Xb + 4194304, Xb + 8388608, biasb);
  cvt_wt<<<dim3(32, 32, 4), dim3(32, 8), 0, stream>>>(Wq, Wk, Wv, Wo, Wt);
  gemm128<<<dim3(8, 32, 3), 256, 0, stream>>>(Xb, Wt, Qb, Kb, Vtb, nullptr, -1);
  attn_pv<<<dim3(32, 16, 2), 256, 0, stream>>>(Qb, Kb, Vtb, biasb, mLb, invlb, ctxb);
  attn_mean<<<dim3(32, 16, 2), 256, 0, stream>>>(Qb, Kb, biasb, mLb, invlb, meanF);
  gemm128<<<dim3(8, 32, 1), 256, 0, stream>>>(ctxb, Wt + 3 * (size_t)HH * HH,
                                              nullptr, nullptr, nullptr, outF, 3);
}